// Round 6
// baseline (17.900 us; speedup 1.0000x reference)
//
#include <hip/hip_runtime.h>

#define NB 4
#define NGRID 512
#define NTARGET 512
#define NBASIS 8
#define NCH 8

#if defined(__has_builtin)
#if __has_builtin(__builtin_amdgcn_exp2f)
#define EXP2F(x) __builtin_amdgcn_exp2f(x)
#else
#define EXP2F(x) exp2f(x)
#endif
#else
#define EXP2F(x) exp2f(x)
#endif

// Single fused kernel. 256 blocks x 512 threads (8 waves) = 1 block/CU.
// Block = (b, 8-target tile); wave w owns target t = tile*8 + w (all 512 g).
// Phase 1: block stages hw[g,c] = sum_k W[k]*h[b,g,k,c] into LDS via float4.
// Phase 2: per-wave exp loop over all g; 3 shuffles once; direct store.
__global__ __launch_bounds__(512) void final_layer_fused(
    const float* __restrict__ x_grid,    // (B, G, C)
    const float* __restrict__ h_grid,    // (B, G, K, C)
    const float* __restrict__ target_x,  // (B, T, C)
    const float* __restrict__ W,         // (1, K)
    const float* __restrict__ bias,      // (1,)
    const float* __restrict__ sigma,     // (K, C)
    float* __restrict__ out)             // (B, T, C)
{
    __shared__ float shw[NGRID * NCH];   // 16 KB: shw[g*8+c]

    const int tid = threadIdx.x;
    const int l   = tid & 63;
    const int w   = tid >> 6;        // wave 0..7
    const int c   = l & 7;

    const int bi = blockIdx.x;
    const int b  = bi >> 6;              // 64 tiles per batch
    const int t  = (bi & 63) * 8 + w;    // this wave's target

    const float LOG2E = 1.4426950408889634f;

    float sg = sigma[l];             // sigma viewed as [k][c] by lane
    float s0 = sigma[c];             // sigma[0][c]
    bool uniform = __all(sg == s0);  // lengthscales uniform across k?

    float tx = target_x[((size_t)b * NTARGET + t) * NCH + c];
    float b0 = bias[0];

    const float* hb = h_grid + (size_t)b * NGRID * 64;
    const float* xb = x_grid + (size_t)b * NGRID * NCH;

    if (uniform) {
        // ---- Phase 1: stage hw into LDS with float4 loads ----
        float w0 = W[0], w1 = W[1], w2 = W[2], w3 = W[3];
        float w4 = W[4], w5 = W[5], w6 = W[6], w7 = W[7];
        const float4* hb4 = (const float4*)hb;
        float4* shw4 = (float4*)shw;
#pragma unroll
        for (int qq = 0; qq < 2; ++qq) {
            int q = tid + qq * 512;               // task: g = q>>1, cquad = q&1
            const float4* hp = hb4 + (q >> 1) * 16 + (q & 1);  // + k*2 per k
            float4 h0 = hp[0],  h1 = hp[2],  h2 = hp[4],  h3 = hp[6];
            float4 h4 = hp[8],  h5 = hp[10], h6 = hp[12], h7 = hp[14];
            float4 a;
            a.x = w0 * h0.x; a.y = w0 * h0.y; a.z = w0 * h0.z; a.w = w0 * h0.w;
            a.x = fmaf(w1, h1.x, a.x); a.y = fmaf(w1, h1.y, a.y);
            a.z = fmaf(w1, h1.z, a.z); a.w = fmaf(w1, h1.w, a.w);
            a.x = fmaf(w2, h2.x, a.x); a.y = fmaf(w2, h2.y, a.y);
            a.z = fmaf(w2, h2.z, a.z); a.w = fmaf(w2, h2.w, a.w);
            a.x = fmaf(w3, h3.x, a.x); a.y = fmaf(w3, h3.y, a.y);
            a.z = fmaf(w3, h3.z, a.z); a.w = fmaf(w3, h3.w, a.w);
            a.x = fmaf(w4, h4.x, a.x); a.y = fmaf(w4, h4.y, a.y);
            a.z = fmaf(w4, h4.z, a.z); a.w = fmaf(w4, h4.w, a.w);
            a.x = fmaf(w5, h5.x, a.x); a.y = fmaf(w5, h5.y, a.y);
            a.z = fmaf(w5, h5.z, a.z); a.w = fmaf(w5, h5.w, a.w);
            a.x = fmaf(w6, h6.x, a.x); a.y = fmaf(w6, h6.y, a.y);
            a.z = fmaf(w6, h6.z, a.z); a.w = fmaf(w6, h6.w, a.w);
            a.x = fmaf(w7, h7.x, a.x); a.y = fmaf(w7, h7.y, a.y);
            a.z = fmaf(w7, h7.z, a.z); a.w = fmaf(w7, h7.w, a.w);
            shw4[q] = a;                          // b128 LDS write
        }
        __syncthreads();

        // ---- Phase 2: exp loop over all 512 g (64 iters/lane) ----
        float scale = __expf(s0) + 1e-6f;
        float coef2 = -0.5f * LOG2E / (scale * scale);

        float a0 = 0.f, a1 = 0.f, a2 = 0.f, a3 = 0.f;
#pragma unroll 4
        for (int j = 0; j < 64; j += 4) {
            float x0 = xb[64 * (j + 0) + l], h0 = shw[64 * (j + 0) + l];
            float x1 = xb[64 * (j + 1) + l], h1 = shw[64 * (j + 1) + l];
            float x2 = xb[64 * (j + 2) + l], h2 = shw[64 * (j + 2) + l];
            float x3 = xb[64 * (j + 3) + l], h3 = shw[64 * (j + 3) + l];
            float d0 = x0 - tx, d1 = x1 - tx, d2 = x2 - tx, d3 = x3 - tx;
            a0 = fmaf(h0, EXP2F(coef2 * (d0 * d0)), a0);
            a1 = fmaf(h1, EXP2F(coef2 * (d1 * d1)), a1);
            a2 = fmaf(h2, EXP2F(coef2 * (d2 * d2)), a2);
            a3 = fmaf(h3, EXP2F(coef2 * (d3 * d3)), a3);
        }
        float v = (a0 + a1) + (a2 + a3);
        // reduce over gs (lane bits 3..5): lanes 0..7 get full sums per c
        v += __shfl_xor(v, 8);
        v += __shfl_xor(v, 16);
        v += __shfl_xor(v, 32);
        if (l < 8)
            out[((size_t)b * NTARGET + t) * NCH + l] = v + b0;
    } else {
        // ---- general fallback: per-(k,c) lengthscales (never taken here) ----
        float scale = __expf(sg) + 1e-6f;
        float coef2 = -0.5f * LOG2E / (scale * scale);
        float wk = W[l >> 3];
        float acc = 0.f;
        for (int g = 0; g < NGRID; ++g) {
            float hv = hb[(size_t)g * 64 + l];   // lane = (k,c), coalesced
            float xg = xb[g * 8 + c];
            float d  = xg - tx;
            acc = fmaf(hv, EXP2F(coef2 * (d * d)), acc);
        }
        acc *= wk;
        acc += __shfl_xor(acc, 8);
        acc += __shfl_xor(acc, 16);
        acc += __shfl_xor(acc, 32);              // sum over k
        if (l < 8)
            out[((size_t)b * NTARGET + t) * NCH + l] = acc + b0;
    }
}

extern "C" void kernel_launch(void* const* d_in, const int* in_sizes, int n_in,
                              void* d_out, int out_size, void* d_ws, size_t ws_size,
                              hipStream_t stream) {
    const float* x_grid   = (const float*)d_in[0];
    const float* h_grid   = (const float*)d_in[1];
    const float* target_x = (const float*)d_in[2];
    const float* W        = (const float*)d_in[3];
    const float* bias     = (const float*)d_in[4];
    const float* sigma    = (const float*)d_in[5];
    float* out = (float*)d_out;

    final_layer_fused<<<dim3(NB * (NTARGET / 8)), dim3(512), 0, stream>>>(
        x_grid, h_grid, target_x, W, bias, sigma, out);
}

// Round 7
// 15.178 us; speedup vs baseline: 1.1794x; 1.1794x over previous
//
#include <hip/hip_runtime.h>

#define NB 4
#define NGRID 512
#define NTARGET 512
#define NBASIS 8
#define NCH 8

#if defined(__has_builtin)
#if __has_builtin(__builtin_amdgcn_exp2f)
#define EXP2F(x) __builtin_amdgcn_exp2f(x)
#else
#define EXP2F(x) exp2f(x)
#endif
#else
#define EXP2F(x) exp2f(x)
#endif

// 512 blocks x 512 threads (8 waves) = 2 blocks/CU, 4 waves/SIMD.
// Block = (b, 4-target tile). Wave w: target = tile*4 + (w>>1), g-half = w&1.
// Phase 1: block stages hw[g,c] = sum_k W[k]*h[b,g,k,c] into LDS via float4.
// Phase 2: per-wave exp loop over its g-half; 3 shuffles once; LDS combine.
__global__ __launch_bounds__(512) void final_layer_fused(
    const float* __restrict__ x_grid,    // (B, G, C)
    const float* __restrict__ h_grid,    // (B, G, K, C)
    const float* __restrict__ target_x,  // (B, T, C)
    const float* __restrict__ W,         // (1, K)
    const float* __restrict__ bias,      // (1,)
    const float* __restrict__ sigma,     // (K, C)
    float* __restrict__ out)             // (B, T, C)
{
    __shared__ float shw[NGRID * NCH];   // 16 KB: shw[g*8+c]
    __shared__ float lds[8 * 8];         // [wave][c] partials

    const int tid = threadIdx.x;
    const int l   = tid & 63;
    const int w   = tid >> 6;        // 0..7
    const int c   = l & 7;

    const int bi   = blockIdx.x;
    const int b    = bi >> 7;        // 128 tiles per batch
    const int tt   = (bi & 127) * 4; // first target of tile
    const int tl   = w >> 1;         // local target 0..3
    const int t    = tt + tl;
    const int half = w & 1;          // g-half 0/1

    const float LOG2E = 1.4426950408889634f;

    float sg = sigma[l];             // sigma viewed as [k][c] by lane
    float s0 = sigma[c];             // sigma[0][c]
    bool uniform = __all(sg == s0);  // lengthscales uniform across k?

    float tx = target_x[((size_t)b * NTARGET + t) * NCH + c];
    float b0 = bias[0];

    const float* hb = h_grid + (size_t)b * NGRID * 64;
    const size_t bbase = (size_t)b * NGRID * NCH + (size_t)half * (NGRID / 2) * NCH;
    const float* xb = x_grid + bbase;

    float v;
    if (uniform) {
        // ---- Phase 1: stage hw into LDS with float4 loads (2 tasks/thread) ----
        float w0 = W[0], w1 = W[1], w2 = W[2], w3 = W[3];
        float w4 = W[4], w5 = W[5], w6 = W[6], w7 = W[7];
        const float4* hb4 = (const float4*)hb;
        float4* shw4 = (float4*)shw;
#pragma unroll
        for (int qq = 0; qq < 2; ++qq) {
            int q = tid + qq * 512;               // task: g = q>>1, cquad = q&1
            const float4* hp = hb4 + (q >> 1) * 16 + (q & 1);  // + k*2 per k
            float4 h0 = hp[0],  h1 = hp[2],  h2 = hp[4],  h3 = hp[6];
            float4 h4 = hp[8],  h5 = hp[10], h6 = hp[12], h7 = hp[14];
            float4 a;
            a.x = w0 * h0.x; a.y = w0 * h0.y; a.z = w0 * h0.z; a.w = w0 * h0.w;
            a.x = fmaf(w1, h1.x, a.x); a.y = fmaf(w1, h1.y, a.y);
            a.z = fmaf(w1, h1.z, a.z); a.w = fmaf(w1, h1.w, a.w);
            a.x = fmaf(w2, h2.x, a.x); a.y = fmaf(w2, h2.y, a.y);
            a.z = fmaf(w2, h2.z, a.z); a.w = fmaf(w2, h2.w, a.w);
            a.x = fmaf(w3, h3.x, a.x); a.y = fmaf(w3, h3.y, a.y);
            a.z = fmaf(w3, h3.z, a.z); a.w = fmaf(w3, h3.w, a.w);
            a.x = fmaf(w4, h4.x, a.x); a.y = fmaf(w4, h4.y, a.y);
            a.z = fmaf(w4, h4.z, a.z); a.w = fmaf(w4, h4.w, a.w);
            a.x = fmaf(w5, h5.x, a.x); a.y = fmaf(w5, h5.y, a.y);
            a.z = fmaf(w5, h5.z, a.z); a.w = fmaf(w5, h5.w, a.w);
            a.x = fmaf(w6, h6.x, a.x); a.y = fmaf(w6, h6.y, a.y);
            a.z = fmaf(w6, h6.z, a.z); a.w = fmaf(w6, h6.w, a.w);
            a.x = fmaf(w7, h7.x, a.x); a.y = fmaf(w7, h7.y, a.y);
            a.z = fmaf(w7, h7.z, a.z); a.w = fmaf(w7, h7.w, a.w);
            shw4[q] = a;                          // b128 LDS write
        }
        __syncthreads();

        // ---- Phase 2: exp loop over this wave's g-half (32 iters) ----
        float scale = __expf(s0) + 1e-6f;
        float coef2 = -0.5f * LOG2E / (scale * scale);
        const float* hwb = shw + half * (NGRID / 2) * NCH;

        float a0 = 0.f, a1 = 0.f, a2 = 0.f, a3 = 0.f;
#pragma unroll
        for (int j = 0; j < 32; j += 4) {
            float x0 = xb[64 * (j + 0) + l], h0 = hwb[64 * (j + 0) + l];
            float x1 = xb[64 * (j + 1) + l], h1 = hwb[64 * (j + 1) + l];
            float x2 = xb[64 * (j + 2) + l], h2 = hwb[64 * (j + 2) + l];
            float x3 = xb[64 * (j + 3) + l], h3 = hwb[64 * (j + 3) + l];
            float d0 = x0 - tx, d1 = x1 - tx, d2 = x2 - tx, d3 = x3 - tx;
            a0 = fmaf(h0, EXP2F(coef2 * (d0 * d0)), a0);
            a1 = fmaf(h1, EXP2F(coef2 * (d1 * d1)), a1);
            a2 = fmaf(h2, EXP2F(coef2 * (d2 * d2)), a2);
            a3 = fmaf(h3, EXP2F(coef2 * (d3 * d3)), a3);
        }
        v = (a0 + a1) + (a2 + a3);
    } else {
        // ---- general fallback: per-(k,c) lengthscales, h read directly ----
        float coef2k[NBASIS], wv[NBASIS];
#pragma unroll
        for (int k = 0; k < NBASIS; ++k) {
            float s = __expf(sigma[k * 8 + c]) + 1e-6f;
            coef2k[k] = -0.5f * LOG2E / (s * s);
            wv[k] = W[k];
        }
        const int gs = l >> 3;
        const float* hbh = hb + (size_t)half * (NGRID / 2) * 64;
        float acc = 0.f;
        for (int j = 0; j < 32; ++j) {
            int g = j * 8 + gs;
            float xg = xb[g * 8 + c];
            float d  = xg - tx;
            float d2 = d * d;
#pragma unroll
            for (int k = 0; k < NBASIS; ++k) {
                float hv = hbh[(size_t)g * 64 + k * 8 + c];
                acc = fmaf(wv[k] * hv, EXP2F(coef2k[k] * d2), acc);
            }
        }
        v = acc;
    }

    // reduce over gs (lane bits 3..5) — 3 shuffles once per wave
    v += __shfl_xor(v, 8);
    v += __shfl_xor(v, 16);
    v += __shfl_xor(v, 32);
    if (l < 8) lds[w * 8 + l] = v;
    __syncthreads();

    // combine the two g-halves: 32 threads -> 4 targets x 8 channels
    if (tid < 32) {
        int tl2 = tid >> 3, cc = tid & 7;
        float r = lds[tl2 * 16 + cc] + lds[tl2 * 16 + 8 + cc] + b0;
        out[((size_t)b * NTARGET + (tt + tl2)) * NCH + cc] = r;
    }
}

extern "C" void kernel_launch(void* const* d_in, const int* in_sizes, int n_in,
                              void* d_out, int out_size, void* d_ws, size_t ws_size,
                              hipStream_t stream) {
    const float* x_grid   = (const float*)d_in[0];
    const float* h_grid   = (const float*)d_in[1];
    const float* target_x = (const float*)d_in[2];
    const float* W        = (const float*)d_in[3];
    const float* bias     = (const float*)d_in[4];
    const float* sigma    = (const float*)d_in[5];
    float* out = (float*)d_out;

    final_layer_fused<<<dim3(NB * (NTARGET / 4)), dim3(512), 0, stream>>>(
        x_grid, h_grid, target_x, W, bias, sigma, out);
}

// Round 8
// 10.352 us; speedup vs baseline: 1.7291x; 1.4662x over previous
//
#include <hip/hip_runtime.h>

#define NB 4
#define NGRID 512
#define NTARGET 512
#define NBASIS 8
#define NCH 8

#if defined(__has_builtin)
#if __has_builtin(__builtin_amdgcn_exp2f)
#define EXP2F(x) __builtin_amdgcn_exp2f(x)
#else
#define EXP2F(x) exp2f(x)
#endif
#else
#define EXP2F(x) exp2f(x)
#endif

// 256 blocks x 1024 threads (16 waves) = 1 block/CU, 4 waves/SIMD.
// Block = (b, 8-target tile). Wave w: target = tile*8 + (w>>1), g-half = w&1.
// Phase 1: block stages hw[g,c] = sum_k W[k]*h[b,g,k,c] into LDS (scalar, R5 form).
// Phase 2: per-wave exp loop over its g-half; 3 shuffles once; LDS combine.
__global__ __launch_bounds__(1024) void final_layer_fused(
    const float* __restrict__ x_grid,    // (B, G, C)
    const float* __restrict__ h_grid,    // (B, G, K, C)
    const float* __restrict__ target_x,  // (B, T, C)
    const float* __restrict__ W,         // (1, K)
    const float* __restrict__ bias,      // (1,)
    const float* __restrict__ sigma,     // (K, C)
    float* __restrict__ out)             // (B, T, C)
{
    __shared__ float shw[NGRID * NCH];   // 16 KB: shw[g*8+c]
    __shared__ float lds[16 * 8];        // [wave][c] partials

    const int tid = threadIdx.x;
    const int l   = tid & 63;
    const int w   = tid >> 6;        // 0..15
    const int c   = l & 7;

    const int bi   = blockIdx.x;
    const int b    = bi >> 6;        // 64 tiles per batch
    const int tt   = (bi & 63) * 8;  // first target of tile
    const int tl   = w >> 1;         // local target 0..7
    const int t    = tt + tl;
    const int half = w & 1;          // g-half 0/1

    const float LOG2E = 1.4426950408889634f;

    float sg = sigma[l];             // sigma viewed as [k][c] by lane
    float s0 = sigma[c];             // sigma[0][c]
    bool uniform = __all(sg == s0);  // lengthscales uniform across k?

    float tx = target_x[((size_t)b * NTARGET + t) * NCH + c];
    float b0 = bias[0];

    const float* hb = h_grid + (size_t)b * NGRID * 64;
    const size_t bbase = (size_t)b * NGRID * NCH + (size_t)half * (NGRID / 2) * NCH;
    const float* xb = x_grid + bbase;

    float v;
    if (uniform) {
        // ---- Phase 1: stage hw into LDS; 4 values/thread, 8-FMA k-loop ----
        float w0 = W[0], w1 = W[1], w2 = W[2], w3 = W[3];
        float w4 = W[4], w5 = W[5], w6 = W[6], w7 = W[7];
#pragma unroll
        for (int vi = 0; vi < 4; ++vi) {
            int f = tid + vi * 1024;          // 0..4095 = g*8 + c
            const float* hp = hb + (size_t)(f >> 3) * 64 + (f & 7);
            float acc;
            acc = w0 * hp[0];
            acc = fmaf(w1, hp[8],  acc);
            acc = fmaf(w2, hp[16], acc);
            acc = fmaf(w3, hp[24], acc);
            acc = fmaf(w4, hp[32], acc);
            acc = fmaf(w5, hp[40], acc);
            acc = fmaf(w6, hp[48], acc);
            acc = fmaf(w7, hp[56], acc);
            shw[f] = acc;
        }
        __syncthreads();

        // ---- Phase 2: exp loop over this wave's g-half (32 iters) ----
        float scale = __expf(s0) + 1e-6f;
        float coef2 = -0.5f * LOG2E / (scale * scale);
        const float* hwb = shw + half * (NGRID / 2) * NCH;

        float a0 = 0.f, a1 = 0.f, a2 = 0.f, a3 = 0.f;
#pragma unroll
        for (int j = 0; j < 32; j += 4) {
            float x0 = xb[64 * (j + 0) + l], h0 = hwb[64 * (j + 0) + l];
            float x1 = xb[64 * (j + 1) + l], h1 = hwb[64 * (j + 1) + l];
            float x2 = xb[64 * (j + 2) + l], h2 = hwb[64 * (j + 2) + l];
            float x3 = xb[64 * (j + 3) + l], h3 = hwb[64 * (j + 3) + l];
            float d0 = x0 - tx, d1 = x1 - tx, d2 = x2 - tx, d3 = x3 - tx;
            a0 = fmaf(h0, EXP2F(coef2 * (d0 * d0)), a0);
            a1 = fmaf(h1, EXP2F(coef2 * (d1 * d1)), a1);
            a2 = fmaf(h2, EXP2F(coef2 * (d2 * d2)), a2);
            a3 = fmaf(h3, EXP2F(coef2 * (d3 * d3)), a3);
        }
        v = (a0 + a1) + (a2 + a3);
    } else {
        // ---- general fallback: per-(k,c) lengthscales, h read directly ----
        float coef2k[NBASIS], wv[NBASIS];
#pragma unroll
        for (int k = 0; k < NBASIS; ++k) {
            float s = __expf(sigma[k * 8 + c]) + 1e-6f;
            coef2k[k] = -0.5f * LOG2E / (s * s);
            wv[k] = W[k];
        }
        const int gs = l >> 3;
        const float* hbh = hb + (size_t)half * (NGRID / 2) * 64;
        float acc = 0.f;
        for (int j = 0; j < 32; ++j) {
            int g = j * 8 + gs;
            float xg = xb[g * 8 + c];
            float d  = xg - tx;
            float d2 = d * d;
#pragma unroll
            for (int k = 0; k < NBASIS; ++k) {
                float hv = hbh[(size_t)g * 64 + k * 8 + c];
                acc = fmaf(wv[k] * hv, EXP2F(coef2k[k] * d2), acc);
            }
        }
        v = acc;
    }

    // reduce over gs (lane bits 3..5) — 3 shuffles once per wave
    v += __shfl_xor(v, 8);
    v += __shfl_xor(v, 16);
    v += __shfl_xor(v, 32);
    if (l < 8) lds[w * 8 + l] = v;
    __syncthreads();

    // combine the two g-halves: 64 threads -> 8 targets x 8 channels
    if (tid < 64) {
        int tl2 = tid >> 3, cc = tid & 7;
        float r = lds[(tl2 * 2) * 8 + cc] + lds[(tl2 * 2 + 1) * 8 + cc] + b0;
        out[((size_t)b * NTARGET + (tt + tl2)) * NCH + cc] = r;
    }
}

extern "C" void kernel_launch(void* const* d_in, const int* in_sizes, int n_in,
                              void* d_out, int out_size, void* d_ws, size_t ws_size,
                              hipStream_t stream) {
    const float* x_grid   = (const float*)d_in[0];
    const float* h_grid   = (const float*)d_in[1];
    const float* target_x = (const float*)d_in[2];
    const float* W        = (const float*)d_in[3];
    const float* bias     = (const float*)d_in[4];
    const float* sigma    = (const float*)d_in[5];
    float* out = (float*)d_out;

    final_layer_fused<<<dim3(NB * (NTARGET / 8)), dim3(1024), 0, stream>>>(
        x_grid, h_grid, target_x, W, bias, sigma, out);
}